// Round 2
// baseline (361.915 us; speedup 1.0000x reference)
//
#include <hip/hip_runtime.h>
#include <hip/hip_bf16.h>
#include <stdint.h>

typedef __bf16 bf16_t;
typedef __bf16 bf16x8 __attribute__((ext_vector_type(8)));
typedef float f32x4 __attribute__((ext_vector_type(4)));

#define B_  8
#define S_  1024
#define D_  1024
#define H_  16
#define DH_ 64

static __device__ __forceinline__ f32x4 mfma_bf16(bf16x8 a, bf16x8 b, f32x4 c) {
  return __builtin_amdgcn_mfma_f32_16x16x32_bf16(a, b, c, 0, 0, 0);
}

// ---------------------------------------------------------------------------
// Transpose four 1024x1024 f32 weights -> bf16 transposed: Wt[n][k] = W[k][n]
// grid (16,16,4), block 256
// ---------------------------------------------------------------------------
__global__ __launch_bounds__(256) void transpose4(
    const float* __restrict__ w0, const float* __restrict__ w1,
    const float* __restrict__ w2, const float* __restrict__ w3,
    bf16_t* __restrict__ t0, bf16_t* __restrict__ t1,
    bf16_t* __restrict__ t2, bf16_t* __restrict__ t3)
{
  __shared__ float tile[64][65];
  const float* src; bf16_t* dst;
  switch (blockIdx.z) {
    case 0: src = w0; dst = t0; break;
    case 1: src = w1; dst = t1; break;
    case 2: src = w2; dst = t2; break;
    default: src = w3; dst = t3; break;
  }
  const int tx = threadIdx.x & 63;
  const int ty = threadIdx.x >> 6;
  const int c0 = blockIdx.x * 64, r0 = blockIdx.y * 64;
#pragma unroll
  for (int r = ty; r < 64; r += 4)
    tile[r][tx] = src[(size_t)(r0 + r) * 1024 + c0 + tx];
  __syncthreads();
#pragma unroll
  for (int r = ty; r < 64; r += 4)
    dst[(size_t)(c0 + r) * 1024 + r0 + tx] = (bf16_t)tile[tx][r];
}

// ---------------------------------------------------------------------------
// Projection GEMM: C = A[M,K](f32) @ Bt[N,K](bf16)^T, scatter C into
// [B,H,S,64] bf16 (row=(b,s), col=(h,d)).
// 128x128 tile, BK=32, 256 thr = 2x2 waves, 4x4 16x16x32 MFMA frags per wave.
// grid (N/128, M/128, z) with z selecting {A,C} pointer set.
// ---------------------------------------------------------------------------
__global__ __launch_bounds__(256) void gemm_proj(
    const float* __restrict__ A0, const float* __restrict__ A1, const float* __restrict__ A2,
    const bf16_t* __restrict__ B0, const bf16_t* __restrict__ B1, const bf16_t* __restrict__ B2,
    bf16_t* __restrict__ C0, bf16_t* __restrict__ C1, bf16_t* __restrict__ C2,
    int M, int N, int K)
{
  const float* Ap; const bf16_t* Bp; bf16_t* Cp;
  if (blockIdx.z == 0)      { Ap = A0; Bp = B0; Cp = C0; }
  else if (blockIdx.z == 1) { Ap = A1; Bp = B1; Cp = C1; }
  else                      { Ap = A2; Bp = B2; Cp = C2; }

  __shared__ bf16_t As[128 * 32];
  __shared__ bf16_t Bs[128 * 32];

  const int tid  = threadIdx.x;
  const int wave = tid >> 6;
  const int lane = tid & 63;
  const int wm   = wave >> 1;
  const int wn   = wave & 1;
  const int quad = lane >> 4;
  const int l15  = lane & 15;

  const int ar = tid >> 2;         // 0..63
  const int ak = (tid & 3) << 3;   // 0,8,16,24

  const int rowA0 = blockIdx.y * 128 + ar;
  const int rowB0 = blockIdx.x * 128 + ar;

  f32x4 acc[4][4];
#pragma unroll
  for (int mi = 0; mi < 4; ++mi)
#pragma unroll
    for (int ni = 0; ni < 4; ++ni)
      acc[mi][ni] = (f32x4){0.f, 0.f, 0.f, 0.f};

  for (int k0 = 0; k0 < K; k0 += 32) {
    // A: f32 -> bf16 in registers
    float4 a0l = *(const float4*)(Ap + (size_t)rowA0 * K + k0 + ak);
    float4 a0h = *(const float4*)(Ap + (size_t)rowA0 * K + k0 + ak + 4);
    float4 a1l = *(const float4*)(Ap + (size_t)(rowA0 + 64) * K + k0 + ak);
    float4 a1h = *(const float4*)(Ap + (size_t)(rowA0 + 64) * K + k0 + ak + 4);
    bf16x8 b0 = *(const bf16x8*)(Bp + (size_t)rowB0 * K + k0 + ak);
    bf16x8 b1 = *(const bf16x8*)(Bp + (size_t)(rowB0 + 64) * K + k0 + ak);
    bf16x8 a0, a1;
    a0[0] = (bf16_t)a0l.x; a0[1] = (bf16_t)a0l.y; a0[2] = (bf16_t)a0l.z; a0[3] = (bf16_t)a0l.w;
    a0[4] = (bf16_t)a0h.x; a0[5] = (bf16_t)a0h.y; a0[6] = (bf16_t)a0h.z; a0[7] = (bf16_t)a0h.w;
    a1[0] = (bf16_t)a1l.x; a1[1] = (bf16_t)a1l.y; a1[2] = (bf16_t)a1l.z; a1[3] = (bf16_t)a1l.w;
    a1[4] = (bf16_t)a1h.x; a1[5] = (bf16_t)a1h.y; a1[6] = (bf16_t)a1h.z; a1[7] = (bf16_t)a1h.w;

    __syncthreads();   // previous iteration's LDS reads complete
    *(bf16x8*)(As + ar * 32 + ak)        = a0;
    *(bf16x8*)(As + (ar + 64) * 32 + ak) = a1;
    *(bf16x8*)(Bs + ar * 32 + ak)        = b0;
    *(bf16x8*)(Bs + (ar + 64) * 32 + ak) = b1;
    __syncthreads();

    bf16x8 af[4], bfr[4];
#pragma unroll
    for (int mi = 0; mi < 4; ++mi)
      af[mi] = *(const bf16x8*)(As + (wm * 64 + mi * 16 + l15) * 32 + quad * 8);
#pragma unroll
    for (int ni = 0; ni < 4; ++ni)
      bfr[ni] = *(const bf16x8*)(Bs + (wn * 64 + ni * 16 + l15) * 32 + quad * 8);
#pragma unroll
    for (int mi = 0; mi < 4; ++mi)
#pragma unroll
      for (int ni = 0; ni < 4; ++ni)
        acc[mi][ni] = mfma_bf16(af[mi], bfr[ni], acc[mi][ni]);
  }

#pragma unroll
  for (int mi = 0; mi < 4; ++mi) {
#pragma unroll
    for (int ni = 0; ni < 4; ++ni) {
#pragma unroll
      for (int r = 0; r < 4; ++r) {
        const int row = blockIdx.y * 128 + wm * 64 + mi * 16 + quad * 4 + r;
        const int col = blockIdx.x * 128 + wn * 64 + ni * 16 + l15;
        const int b = row >> 10, s = row & 1023;
        const int h = col >> 6,  d = col & 63;
        Cp[(((size_t)(b * H_ + h) << 10) | s) * DH_ + d] = (bf16_t)acc[mi][ni][r];
      }
    }
  }
}

// ---------------------------------------------------------------------------
// Output GEMM: C[M,N](f32) = A[M,K](bf16) @ Bt[N,K](bf16)^T, row-major C.
// Same tiling as gemm_proj. grid (N/128, M/128, 1).
// ---------------------------------------------------------------------------
__global__ __launch_bounds__(256) void gemm_out(
    const bf16_t* __restrict__ Ap, const bf16_t* __restrict__ Bp,
    float* __restrict__ Cp, int M, int N, int K)
{
  __shared__ bf16_t As[128 * 32];
  __shared__ bf16_t Bs[128 * 32];

  const int tid  = threadIdx.x;
  const int wave = tid >> 6;
  const int lane = tid & 63;
  const int wm   = wave >> 1;
  const int wn   = wave & 1;
  const int quad = lane >> 4;
  const int l15  = lane & 15;

  const int ar = tid >> 2;
  const int ak = (tid & 3) << 3;

  const int rowA0 = blockIdx.y * 128 + ar;
  const int rowB0 = blockIdx.x * 128 + ar;

  f32x4 acc[4][4];
#pragma unroll
  for (int mi = 0; mi < 4; ++mi)
#pragma unroll
    for (int ni = 0; ni < 4; ++ni)
      acc[mi][ni] = (f32x4){0.f, 0.f, 0.f, 0.f};

  for (int k0 = 0; k0 < K; k0 += 32) {
    bf16x8 a0 = *(const bf16x8*)(Ap + (size_t)rowA0 * K + k0 + ak);
    bf16x8 a1 = *(const bf16x8*)(Ap + (size_t)(rowA0 + 64) * K + k0 + ak);
    bf16x8 b0 = *(const bf16x8*)(Bp + (size_t)rowB0 * K + k0 + ak);
    bf16x8 b1 = *(const bf16x8*)(Bp + (size_t)(rowB0 + 64) * K + k0 + ak);
    __syncthreads();
    *(bf16x8*)(As + ar * 32 + ak)        = a0;
    *(bf16x8*)(As + (ar + 64) * 32 + ak) = a1;
    *(bf16x8*)(Bs + ar * 32 + ak)        = b0;
    *(bf16x8*)(Bs + (ar + 64) * 32 + ak) = b1;
    __syncthreads();

    bf16x8 af[4], bfr[4];
#pragma unroll
    for (int mi = 0; mi < 4; ++mi)
      af[mi] = *(const bf16x8*)(As + (wm * 64 + mi * 16 + l15) * 32 + quad * 8);
#pragma unroll
    for (int ni = 0; ni < 4; ++ni)
      bfr[ni] = *(const bf16x8*)(Bs + (wn * 64 + ni * 16 + l15) * 32 + quad * 8);
#pragma unroll
    for (int mi = 0; mi < 4; ++mi)
#pragma unroll
      for (int ni = 0; ni < 4; ++ni)
        acc[mi][ni] = mfma_bf16(af[mi], bfr[ni], acc[mi][ni]);
  }

#pragma unroll
  for (int mi = 0; mi < 4; ++mi) {
#pragma unroll
    for (int ni = 0; ni < 4; ++ni) {
#pragma unroll
      for (int r = 0; r < 4; ++r) {
        const int row = blockIdx.y * 128 + wm * 64 + mi * 16 + quad * 4 + r;
        const int col = blockIdx.x * 128 + wn * 64 + ni * 16 + l15;
        Cp[(size_t)row * N + col] = acc[mi][ni][r];
      }
    }
  }
}

// ---------------------------------------------------------------------------
// Flash attention, dh=64, Q/K/V bf16 in [B,H,S,64].
// Block = 256 thr = 4 waves; wave handles 16 q-rows; block q-tile = 64 rows.
// Only ceil(L/64) key-tiles processed (mask == softmax over first L keys).
// Out: [B,S,H*64] bf16.  grid (S/64, H, B)
// ---------------------------------------------------------------------------
__global__ __launch_bounds__(256) void attn64(
    const bf16_t* __restrict__ Q,
    const bf16_t* __restrict__ Kv,
    const bf16_t* __restrict__ V,
    const int* __restrict__ valid_lens,
    bf16_t* __restrict__ O)
{
  const int qt = blockIdx.x;
  const int h  = blockIdx.y;
  const int b  = blockIdx.z;
  const int tid  = threadIdx.x;
  const int wave = tid >> 6;
  const int lane = tid & 63;
  const int quad = lane >> 4;
  const int l15  = lane & 15;

  const int L   = valid_lens[b];
  const int nkt = (L + 63) >> 6;

  const size_t base = ((size_t)(b * H_ + h)) * S_ * DH_;
  const bf16_t* Qp = Q  + base;
  const bf16_t* Kp = Kv + base;
  const bf16_t* Vp = V  + base;

  __shared__ bf16_t Vt[64 * 72];       // [d][key], stride 72
  __shared__ bf16_t Pb[4][16 * 72];    // per-wave P [q][key]

  const int qrow = qt * 64 + wave * 16 + l15;
  const bf16x8 qf0 = *(const bf16x8*)(Qp + (size_t)qrow * DH_ + quad * 8);
  const bf16x8 qf1 = *(const bf16x8*)(Qp + (size_t)qrow * DH_ + 32 + quad * 8);

  f32x4 o[4];
  float m_r[4], l_r[4];
#pragma unroll
  for (int r = 0; r < 4; ++r) {
    o[r] = (f32x4){0.f, 0.f, 0.f, 0.f};
    m_r[r] = -1e30f;
    l_r[r] = 0.f;
  }

  const int vkey = tid & 63;
  const int vd0  = (tid >> 6) * 16;

  for (int kt = 0; kt < nkt; ++kt) {
    const bf16_t* vrow = Vp + (size_t)(kt * 64 + vkey) * DH_ + vd0;
    bf16x8 v0 = *(const bf16x8*)(vrow);
    bf16x8 v1 = *(const bf16x8*)(vrow + 8);
    __syncthreads();   // prior iteration's Vt/Pb reads complete
#pragma unroll
    for (int j = 0; j < 8; ++j) {
      Vt[(vd0 + j) * 72 + vkey]     = v0[j];
      Vt[(vd0 + 8 + j) * 72 + vkey] = v1[j];
    }

    f32x4 sc[4];
#pragma unroll
    for (int n16 = 0; n16 < 4; ++n16) {
      const bf16_t* krow = Kp + (size_t)(kt * 64 + n16 * 16 + l15) * DH_;
      bf16x8 kf0 = *(const bf16x8*)(krow + quad * 8);
      bf16x8 kf1 = *(const bf16x8*)(krow + 32 + quad * 8);
      f32x4 s = (f32x4){0.f, 0.f, 0.f, 0.f};
      s = mfma_bf16(qf0, kf0, s);
      s = mfma_bf16(qf1, kf1, s);
      sc[n16] = s;
    }

#pragma unroll
    for (int n16 = 0; n16 < 4; ++n16) {
      const int key = kt * 64 + n16 * 16 + l15;
      const bool valid = (key < L);
#pragma unroll
      for (int r = 0; r < 4; ++r) {
        const float s = sc[n16][r] * 0.125f;
        sc[n16][r] = valid ? s : -1e30f;
      }
    }

    float tmax[4];
#pragma unroll
    for (int r = 0; r < 4; ++r) {
      float t = fmaxf(fmaxf(sc[0][r], sc[1][r]), fmaxf(sc[2][r], sc[3][r]));
      t = fmaxf(t, __shfl_xor(t, 1, 64));
      t = fmaxf(t, __shfl_xor(t, 2, 64));
      t = fmaxf(t, __shfl_xor(t, 4, 64));
      t = fmaxf(t, __shfl_xor(t, 8, 64));
      tmax[r] = t;
    }

    float alpha[4];
#pragma unroll
    for (int r = 0; r < 4; ++r) {
      const float mn = fmaxf(m_r[r], tmax[r]);
      alpha[r] = __expf(m_r[r] - mn);
      m_r[r] = mn;
    }

    float rsum[4] = {0.f, 0.f, 0.f, 0.f};
#pragma unroll
    for (int n16 = 0; n16 < 4; ++n16) {
#pragma unroll
      for (int r = 0; r < 4; ++r) {
        const float p = __expf(sc[n16][r] - m_r[r]);
        rsum[r] += p;
        Pb[wave][(quad * 4 + r) * 72 + n16 * 16 + l15] = (bf16_t)p;
      }
    }
#pragma unroll
    for (int r = 0; r < 4; ++r) {
      float t = rsum[r];
      t += __shfl_xor(t, 1, 64);
      t += __shfl_xor(t, 2, 64);
      t += __shfl_xor(t, 4, 64);
      t += __shfl_xor(t, 8, 64);
      l_r[r] = l_r[r] * alpha[r] + t;
    }

#pragma unroll
    for (int dt = 0; dt < 4; ++dt)
#pragma unroll
      for (int r = 0; r < 4; ++r)
        o[dt][r] *= alpha[r];

    __syncthreads();   // Vt fully staged; Pb write->read ordered

    const bf16x8 pf0 = *(const bf16x8*)(&Pb[wave][l15 * 72 + quad * 8]);
    const bf16x8 pf1 = *(const bf16x8*)(&Pb[wave][l15 * 72 + 32 + quad * 8]);
#pragma unroll
    for (int dt = 0; dt < 4; ++dt) {
      bf16x8 vf0 = *(const bf16x8*)(&Vt[(dt * 16 + l15) * 72 + quad * 8]);
      bf16x8 vf1 = *(const bf16x8*)(&Vt[(dt * 16 + l15) * 72 + 32 + quad * 8]);
      o[dt] = mfma_bf16(pf0, vf0, o[dt]);
      o[dt] = mfma_bf16(pf1, vf1, o[dt]);
    }
  }

#pragma unroll
  for (int r = 0; r < 4; ++r) l_r[r] = 1.f / l_r[r];
  const int qout = qt * 64 + wave * 16 + quad * 4;
#pragma unroll
  for (int dt = 0; dt < 4; ++dt) {
#pragma unroll
    for (int r = 0; r < 4; ++r) {
      const float v = o[dt][r] * l_r[r];
      O[((size_t)(b * S_ + qout + r)) * (H_ * DH_) + h * DH_ + dt * 16 + l15] = (bf16_t)v;
    }
  }
}

// ---------------------------------------------------------------------------
extern "C" void kernel_launch(void* const* d_in, const int* in_sizes, int n_in,
                              void* d_out, int out_size, void* d_ws, size_t ws_size,
                              hipStream_t stream) {
  const float* queries = (const float*)d_in[0];
  const float* keys    = (const float*)d_in[1];
  const float* values  = (const float*)d_in[2];
  const float* Wq      = (const float*)d_in[3];
  const float* Wk      = (const float*)d_in[4];
  const float* Wv      = (const float*)d_in[5];
  const float* Wo      = (const float*)d_in[6];
  const int* valid_lens = (const int*)d_in[7];
  float* out = (float*)d_out;

  bf16_t* ws = (bf16_t*)d_ws;
  const size_t MB = 1024 * 1024;     // elements (bf16)
  bf16_t* WqT = ws + 0 * MB;
  bf16_t* WkT = ws + 1 * MB;
  bf16_t* WvT = ws + 2 * MB;
  bf16_t* WoT = ws + 3 * MB;
  bf16_t* Qb  = ws + 4 * MB;         // [B,H,S,64]  8M elems
  bf16_t* Kb  = ws + 12 * MB;
  bf16_t* Vb  = ws + 20 * MB;
  bf16_t* Ab  = ws + 28 * MB;        // [B,S,1024]  8M elems  (total 72 MB)

  transpose4<<<dim3(16, 16, 4), 256, 0, stream>>>(Wq, Wk, Wv, Wo, WqT, WkT, WvT, WoT);

  gemm_proj<<<dim3(8, 64, 3), 256, 0, stream>>>(queries, keys, values,
                                                WqT, WkT, WvT,
                                                Qb, Kb, Vb,
                                                8192, 1024, 1024);

  attn64<<<dim3(16, 16, 8), 256, 0, stream>>>(Qb, Kb, Vb, valid_lens, Ab);

  gemm_out<<<dim3(8, 64, 1), 256, 0, stream>>>(Ab, WoT, out, 8192, 1024, 1024);
}

// Round 3
// 334.890 us; speedup vs baseline: 1.0807x; 1.0807x over previous
//
#include <hip/hip_runtime.h>
#include <hip/hip_bf16.h>
#include <stdint.h>

typedef __bf16 bf16_t;
typedef __bf16 bf16x8 __attribute__((ext_vector_type(8)));
typedef float f32x4 __attribute__((ext_vector_type(4)));

#define B_  8
#define S_  1024
#define D_  1024
#define H_  16
#define DH_ 64

static __device__ __forceinline__ f32x4 mfma_bf16(bf16x8 a, bf16x8 b, f32x4 c) {
  return __builtin_amdgcn_mfma_f32_16x16x32_bf16(a, b, c, 0, 0, 0);
}

// async global->LDS, 16 bytes per lane; LDS dest = wave-uniform base + lane*16
#define GLOAD_LDS16(g, l)                                                     \
  __builtin_amdgcn_global_load_lds(                                           \
      (const __attribute__((address_space(1))) void*)(g),                     \
      (__attribute__((address_space(3))) void*)(l), 16, 0, 0)

// ---------------------------------------------------------------------------
// Transpose four 1024x1024 f32 weights -> bf16 transposed: Wt[n][k] = W[k][n]
// grid (16,16,4), block 256
// ---------------------------------------------------------------------------
__global__ __launch_bounds__(256) void transpose4(
    const float* __restrict__ w0, const float* __restrict__ w1,
    const float* __restrict__ w2, const float* __restrict__ w3,
    bf16_t* __restrict__ t0, bf16_t* __restrict__ t1,
    bf16_t* __restrict__ t2, bf16_t* __restrict__ t3)
{
  __shared__ float tile[64][65];
  const float* src; bf16_t* dst;
  switch (blockIdx.z) {
    case 0: src = w0; dst = t0; break;
    case 1: src = w1; dst = t1; break;
    case 2: src = w2; dst = t2; break;
    default: src = w3; dst = t3; break;
  }
  const int tx = threadIdx.x & 63;
  const int ty = threadIdx.x >> 6;
  const int c0 = blockIdx.x * 64, r0 = blockIdx.y * 64;
#pragma unroll
  for (int r = ty; r < 64; r += 4)
    tile[r][tx] = src[(size_t)(r0 + r) * 1024 + c0 + tx];
  __syncthreads();
#pragma unroll
  for (int r = ty; r < 64; r += 4)
    dst[(size_t)(c0 + r) * 1024 + r0 + tx] = (bf16_t)tile[tx][r];
}

// ---------------------------------------------------------------------------
// Convert Q/K/V f32 -> bf16 (contiguous). grid (4096,3), block 256, 8 elem/thr.
// ---------------------------------------------------------------------------
__global__ __launch_bounds__(256) void convert_qkv(
    const float* __restrict__ q, const float* __restrict__ k,
    const float* __restrict__ v,
    bf16_t* __restrict__ qo, bf16_t* __restrict__ ko, bf16_t* __restrict__ vo)
{
  const float* src; bf16_t* dst;
  switch (blockIdx.y) {
    case 0: src = q; dst = qo; break;
    case 1: src = k; dst = ko; break;
    default: src = v; dst = vo; break;
  }
  const size_t i = ((size_t)blockIdx.x * 256 + threadIdx.x) * 8;
  float4 a = *(const float4*)(src + i);
  float4 b = *(const float4*)(src + i + 4);
  bf16x8 o;
  o[0] = (bf16_t)a.x; o[1] = (bf16_t)a.y; o[2] = (bf16_t)a.z; o[3] = (bf16_t)a.w;
  o[4] = (bf16_t)b.x; o[5] = (bf16_t)b.y; o[6] = (bf16_t)b.z; o[7] = (bf16_t)b.w;
  *(bf16x8*)(dst + i) = o;
}

// ---------------------------------------------------------------------------
// m97-style GEMM core: C = A[M,K](bf16) @ Bt[N,K](bf16)^T
// 128x128 tile, BK=32, 256 thr = 2x2 waves, 4x4 16x16x32 MFMA frags/wave.
// global_load_lds width=16 staging (LDS layout lane-contiguous, NO padding).
// XCD swizzle: gridDim.x==8 -> blockIdx.x == dispatch_id%8 == XCD; each XCD
// owns 8 consecutive M-tiles x all 8 N-tiles (A+B working set ~4MB = L2).
// mode: 0 = C f32 row-major; 1 = C bf16 scatter into [B,H,S,64].
// ---------------------------------------------------------------------------
template <int MODE>
__device__ __forceinline__ void gemm_core(
    const bf16_t* __restrict__ Ap, const bf16_t* __restrict__ Bp,
    void* __restrict__ Cp, int K, int N)
{
  __shared__ bf16_t As[128 * 32];
  __shared__ bf16_t Bs[128 * 32];

  const int tid  = threadIdx.x;
  const int wv   = tid >> 6;
  const int lane = tid & 63;
  const int wm   = wv >> 1;
  const int wn   = wv & 1;
  const int quad = lane >> 4;
  const int l15  = lane & 15;

  // XCD-aware tile assignment (gridDim 8 x 64)
  const int tileM = blockIdx.x * 8 + (blockIdx.y & 7);   // 0..63
  const int tileN = blockIdx.y >> 3;                     // 0..7

  // staging map: chunk c in [0,512): row=c>>2, col8=(c&3)*8 ; LDS elems = c*8
  const int c0  = wv * 128 + lane;        // instruction j adds j*64
  const int r0  = c0 >> 2;
  const int cl0 = (c0 & 3) << 3;
  const int c1  = c0 + 64;
  const int r1  = c1 >> 2;
  const int cl1 = (c1 & 3) << 3;

  const bf16_t* Arow0 = Ap + (size_t)(tileM * 128 + r0) * K + cl0;
  const bf16_t* Arow1 = Ap + (size_t)(tileM * 128 + r1) * K + cl1;
  const bf16_t* Brow0 = Bp + (size_t)(tileN * 128 + r0) * K + cl0;
  const bf16_t* Brow1 = Bp + (size_t)(tileN * 128 + r1) * K + cl1;

  bf16_t* lA0 = As + (size_t)(wv * 128) * 8;        // + lane*16B implicit
  bf16_t* lA1 = As + (size_t)(wv * 128 + 64) * 8;
  bf16_t* lB0 = Bs + (size_t)(wv * 128) * 8;
  bf16_t* lB1 = Bs + (size_t)(wv * 128 + 64) * 8;

  f32x4 acc[4][4];
#pragma unroll
  for (int mi = 0; mi < 4; ++mi)
#pragma unroll
    for (int ni = 0; ni < 4; ++ni)
      acc[mi][ni] = (f32x4){0.f, 0.f, 0.f, 0.f};

  for (int k0 = 0; k0 < K; k0 += 32) {
    __syncthreads();                 // prior iteration's LDS reads complete
    GLOAD_LDS16(Arow0 + k0, lA0);
    GLOAD_LDS16(Arow1 + k0, lA1);
    GLOAD_LDS16(Brow0 + k0, lB0);
    GLOAD_LDS16(Brow1 + k0, lB1);
    __syncthreads();                 // vmcnt(0) drain + barrier

    bf16x8 af[4], bfr[4];
#pragma unroll
    for (int mi = 0; mi < 4; ++mi)
      af[mi] = *(const bf16x8*)(As + (wm * 64 + mi * 16 + l15) * 32 + quad * 8);
#pragma unroll
    for (int ni = 0; ni < 4; ++ni)
      bfr[ni] = *(const bf16x8*)(Bs + (wn * 64 + ni * 16 + l15) * 32 + quad * 8);
#pragma unroll
    for (int mi = 0; mi < 4; ++mi)
#pragma unroll
      for (int ni = 0; ni < 4; ++ni)
        acc[mi][ni] = mfma_bf16(af[mi], bfr[ni], acc[mi][ni]);
  }

#pragma unroll
  for (int mi = 0; mi < 4; ++mi) {
#pragma unroll
    for (int ni = 0; ni < 4; ++ni) {
#pragma unroll
      for (int r = 0; r < 4; ++r) {
        const int row = tileM * 128 + wm * 64 + mi * 16 + quad * 4 + r;
        const int col = tileN * 128 + wn * 64 + ni * 16 + l15;
        if (MODE == 0) {
          ((float*)Cp)[(size_t)row * N + col] = acc[mi][ni][r];
        } else {
          const int b = row >> 10, s = row & 1023;
          const int h = col >> 6,  d = col & 63;
          ((bf16_t*)Cp)[(((size_t)(b * H_ + h) << 10) | s) * DH_ + d] =
              (bf16_t)acc[mi][ni][r];
        }
      }
    }
  }
}

// Projection GEMM: z selects {A,C}; B = transposed weight. grid (8,64,3).
__global__ __launch_bounds__(256) void gemm_proj(
    const bf16_t* __restrict__ A0, const bf16_t* __restrict__ A1, const bf16_t* __restrict__ A2,
    const bf16_t* __restrict__ B0, const bf16_t* __restrict__ B1, const bf16_t* __restrict__ B2,
    bf16_t* __restrict__ C0, bf16_t* __restrict__ C1, bf16_t* __restrict__ C2)
{
  const bf16_t* Ap; const bf16_t* Bp; bf16_t* Cp;
  if (blockIdx.z == 0)      { Ap = A0; Bp = B0; Cp = C0; }
  else if (blockIdx.z == 1) { Ap = A1; Bp = B1; Cp = C1; }
  else                      { Ap = A2; Bp = B2; Cp = C2; }
  gemm_core<1>(Ap, Bp, (void*)Cp, 1024, 1024);
}

// Output GEMM: f32 row-major C. grid (8,64,1).
__global__ __launch_bounds__(256) void gemm_out(
    const bf16_t* __restrict__ Ap, const bf16_t* __restrict__ Bp,
    float* __restrict__ Cp)
{
  gemm_core<0>(Ap, Bp, (void*)Cp, 1024, 1024);
}

// ---------------------------------------------------------------------------
// Flash attention, dh=64, Q/K/V bf16 in [B,H,S,64].
// Block = 256 thr = 4 waves; wave handles 16 q-rows; block q-tile = 64 rows.
// Only ceil(L/64) key-tiles processed. Out: [B,S,H*64] bf16.  grid (S/64,H,B)
// ---------------------------------------------------------------------------
__global__ __launch_bounds__(256) void attn64(
    const bf16_t* __restrict__ Q,
    const bf16_t* __restrict__ Kv,
    const bf16_t* __restrict__ V,
    const int* __restrict__ valid_lens,
    bf16_t* __restrict__ O)
{
  const int qt = blockIdx.x;
  const int h  = blockIdx.y;
  const int b  = blockIdx.z;
  const int tid  = threadIdx.x;
  const int wave = tid >> 6;
  const int lane = tid & 63;
  const int quad = lane >> 4;
  const int l15  = lane & 15;

  const int L   = valid_lens[b];
  const int nkt = (L + 63) >> 6;

  const size_t base = ((size_t)(b * H_ + h)) * S_ * DH_;
  const bf16_t* Qp = Q  + base;
  const bf16_t* Kp = Kv + base;
  const bf16_t* Vp = V  + base;

  __shared__ bf16_t Vt[64 * 72];       // [d][key], stride 72
  __shared__ bf16_t Pb[4][16 * 72];    // per-wave P [q][key]

  const int qrow = qt * 64 + wave * 16 + l15;
  const bf16x8 qf0 = *(const bf16x8*)(Qp + (size_t)qrow * DH_ + quad * 8);
  const bf16x8 qf1 = *(const bf16x8*)(Qp + (size_t)qrow * DH_ + 32 + quad * 8);

  f32x4 o[4];
  float m_r[4], l_r[4];
#pragma unroll
  for (int r = 0; r < 4; ++r) {
    o[r] = (f32x4){0.f, 0.f, 0.f, 0.f};
    m_r[r] = -1e30f;
    l_r[r] = 0.f;
  }

  const int vkey = tid & 63;
  const int vd0  = (tid >> 6) * 16;

  for (int kt = 0; kt < nkt; ++kt) {
    const bf16_t* vrow = Vp + (size_t)(kt * 64 + vkey) * DH_ + vd0;
    bf16x8 v0 = *(const bf16x8*)(vrow);
    bf16x8 v1 = *(const bf16x8*)(vrow + 8);
    __syncthreads();   // prior iteration's Vt/Pb reads complete
#pragma unroll
    for (int j = 0; j < 8; ++j) {
      Vt[(vd0 + j) * 72 + vkey]     = v0[j];
      Vt[(vd0 + 8 + j) * 72 + vkey] = v1[j];
    }

    f32x4 sc[4];
#pragma unroll
    for (int n16 = 0; n16 < 4; ++n16) {
      const bf16_t* krow = Kp + (size_t)(kt * 64 + n16 * 16 + l15) * DH_;
      bf16x8 kf0 = *(const bf16x8*)(krow + quad * 8);
      bf16x8 kf1 = *(const bf16x8*)(krow + 32 + quad * 8);
      f32x4 s = (f32x4){0.f, 0.f, 0.f, 0.f};
      s = mfma_bf16(qf0, kf0, s);
      s = mfma_bf16(qf1, kf1, s);
      sc[n16] = s;
    }

#pragma unroll
    for (int n16 = 0; n16 < 4; ++n16) {
      const int key = kt * 64 + n16 * 16 + l15;
      const bool valid = (key < L);
#pragma unroll
      for (int r = 0; r < 4; ++r) {
        const float s = sc[n16][r] * 0.125f;
        sc[n16][r] = valid ? s : -1e30f;
      }
    }

    float tmax[4];
#pragma unroll
    for (int r = 0; r < 4; ++r) {
      float t = fmaxf(fmaxf(sc[0][r], sc[1][r]), fmaxf(sc[2][r], sc[3][r]));
      t = fmaxf(t, __shfl_xor(t, 1, 64));
      t = fmaxf(t, __shfl_xor(t, 2, 64));
      t = fmaxf(t, __shfl_xor(t, 4, 64));
      t = fmaxf(t, __shfl_xor(t, 8, 64));
      tmax[r] = t;
    }

    float alpha[4];
#pragma unroll
    for (int r = 0; r < 4; ++r) {
      const float mn = fmaxf(m_r[r], tmax[r]);
      alpha[r] = __expf(m_r[r] - mn);
      m_r[r] = mn;
    }

    float rsum[4] = {0.f, 0.f, 0.f, 0.f};
#pragma unroll
    for (int n16 = 0; n16 < 4; ++n16) {
#pragma unroll
      for (int r = 0; r < 4; ++r) {
        const float p = __expf(sc[n16][r] - m_r[r]);
        rsum[r] += p;
        Pb[wave][(quad * 4 + r) * 72 + n16 * 16 + l15] = (bf16_t)p;
      }
    }
#pragma unroll
    for (int r = 0; r < 4; ++r) {
      float t = rsum[r];
      t += __shfl_xor(t, 1, 64);
      t += __shfl_xor(t, 2, 64);
      t += __shfl_xor(t, 4, 64);
      t += __shfl_xor(t, 8, 64);
      l_r[r] = l_r[r] * alpha[r] + t;
    }

#pragma unroll
    for (int dt = 0; dt < 4; ++dt)
#pragma unroll
      for (int r = 0; r < 4; ++r)
        o[dt][r] *= alpha[r];

    __syncthreads();   // Vt fully staged; Pb write->read ordered

    const bf16x8 pf0 = *(const bf16x8*)(&Pb[wave][l15 * 72 + quad * 8]);
    const bf16x8 pf1 = *(const bf16x8*)(&Pb[wave][l15 * 72 + 32 + quad * 8]);
#pragma unroll
    for (int dt = 0; dt < 4; ++dt) {
      bf16x8 vf0 = *(const bf16x8*)(&Vt[(dt * 16 + l15) * 72 + quad * 8]);
      bf16x8 vf1 = *(const bf16x8*)(&Vt[(dt * 16 + l15) * 72 + 32 + quad * 8]);
      o[dt] = mfma_bf16(pf0, vf0, o[dt]);
      o[dt] = mfma_bf16(pf1, vf1, o[dt]);
    }
  }

#pragma unroll
  for (int r = 0; r < 4; ++r) l_r[r] = 1.f / l_r[r];
  const int qout = qt * 64 + wave * 16 + quad * 4;
#pragma unroll
  for (int dt = 0; dt < 4; ++dt) {
#pragma unroll
    for (int r = 0; r < 4; ++r) {
      const float v = o[dt][r] * l_r[r];
      O[((size_t)(b * S_ + qout + r)) * (H_ * DH_) + h * DH_ + dt * 16 + l15] = (bf16_t)v;
    }
  }
}

// ---------------------------------------------------------------------------
extern "C" void kernel_launch(void* const* d_in, const int* in_sizes, int n_in,
                              void* d_out, int out_size, void* d_ws, size_t ws_size,
                              hipStream_t stream) {
  const float* queries = (const float*)d_in[0];
  const float* keys    = (const float*)d_in[1];
  const float* values  = (const float*)d_in[2];
  const float* Wq      = (const float*)d_in[3];
  const float* Wk      = (const float*)d_in[4];
  const float* Wv      = (const float*)d_in[5];
  const float* Wo      = (const float*)d_in[6];
  const int* valid_lens = (const int*)d_in[7];
  float* out = (float*)d_out;

  bf16_t* ws = (bf16_t*)d_ws;
  const size_t MB = 1024 * 1024;     // elements (bf16)
  bf16_t* WqT = ws + 0 * MB;
  bf16_t* WkT = ws + 1 * MB;
  bf16_t* WvT = ws + 2 * MB;
  bf16_t* WoT = ws + 3 * MB;
  bf16_t* Qc  = ws + 4 * MB;         // bf16 copies of inputs, 8M elems each
  bf16_t* Kc  = ws + 12 * MB;
  bf16_t* Vc  = ws + 20 * MB;
  bf16_t* Qb  = ws + 28 * MB;        // [B,H,S,64] projected, 8M elems each
  bf16_t* Kb  = ws + 36 * MB;
  bf16_t* Vb  = ws + 44 * MB;
  bf16_t* Ab  = ws + 52 * MB;        // [B,S,1024] attn out  (total 120 MB)

  transpose4<<<dim3(16, 16, 4), 256, 0, stream>>>(Wq, Wk, Wv, Wo, WqT, WkT, WvT, WoT);

  convert_qkv<<<dim3(4096, 3), 256, 0, stream>>>(queries, keys, values, Qc, Kc, Vc);

  gemm_proj<<<dim3(8, 64, 3), 256, 0, stream>>>(Qc, Kc, Vc,
                                                WqT, WkT, WvT,
                                                Qb, Kb, Vb);

  attn64<<<dim3(16, 16, 8), 256, 0, stream>>>(Qb, Kb, Vb, valid_lens, Ab);

  gemm_out<<<dim3(8, 64, 1), 256, 0, stream>>>(Ab, WoT, out);
}